// Round 1
// baseline (939.562 us; speedup 1.0000x reference)
//
#include <hip/hip_runtime.h>

// MLA forward. Inputs f32, internal bf16 MFMA 16x16x32, output f32.
// R8: k_attn rework — drop LDS K-staging (K/V are L2-resident after XCD
// swizzle; 4 waves/block share the tile via L1), drop both per-iteration
// __syncthreads (only raw s_barrier for lockstep), split into one q-tile
// per block (grid 512->1024, big tiles dispatched first). LDS 43KB->9KB,
// launch_bounds(256,4) -> 4 blocks/CU (16 waves/CU vs 8).

typedef __attribute__((ext_vector_type(8))) short short8;
typedef __attribute__((ext_vector_type(4))) float floatx4;
typedef unsigned short u16;
typedef unsigned int u32;

__device__ __forceinline__ float bf2f(u16 u){ u32 x=((u32)u)<<16; return __builtin_bit_cast(float,x); }
__device__ __forceinline__ u16 f2bf(float f){ u32 x=__builtin_bit_cast(u32,f); return (u16)((x + 0x7fffu + ((x>>16)&1u))>>16); }

__device__ __forceinline__ floatx4 mfma16(short8 a, short8 b, floatx4 c){
  return __builtin_amdgcn_mfma_f32_16x16x32_bf16(a,b,c,0,0,0);
}

// async global->LDS, 16B per lane. LDS dest = wave-uniform base + lane*16.
__device__ __forceinline__ void gl_lds16(const u16* g, u16* l){
  __builtin_amdgcn_global_load_lds((const __attribute__((address_space(1))) void*)g,
                                   (__attribute__((address_space(3))) void*)l, 16, 0, 0);
}

// ---------- f32 -> bf16 elementwise (for x) ----------
__global__ __launch_bounds__(256)
void k_f2b(const float* __restrict__ in, u16* __restrict__ out, size_t n){
  size_t i = ((size_t)blockIdx.x*256 + threadIdx.x)*4;
  if(i >= n) return;
  float4 v = *(const float4*)(in + i);
  out[i+0] = f2bf(v.x); out[i+1] = f2bf(v.y); out[i+2] = f2bf(v.z); out[i+3] = f2bf(v.w);
}

// ---------- transpose + convert: f32 [K,N] -> bf16 [N,K] ----------
__global__ void k_transpose(const float* __restrict__ in, u16* __restrict__ out, int K, int N){
  __shared__ u16 tile[32][33];
  const int kb = blockIdx.y*32, nb = blockIdx.x*32;
  const int tx = threadIdx.x, ty = threadIdx.y;
#pragma unroll
  for(int i=0;i<4;i++) tile[ty+i*8][tx] = f2bf(in[(size_t)(kb+ty+i*8)*N + nb + tx]);
  __syncthreads();
#pragma unroll
  for(int i=0;i<4;i++) out[(size_t)(nb+ty+i*8)*K + kb + tx] = tile[tx][ty+i*8];
}

// ---------- rope table (fp64 for large-angle accuracy) ----------
__global__ void k_rope_table(float* __restrict__ cosT, float* __restrict__ sinT){
  int idx = blockIdx.x*256 + threadIdx.x;
  if(idx >= 2048*64) return;
  int p = idx>>6, i = idx&63;
  double freq = pow(10000.0, -(double)(2*i)/128.0) * 40.0;
  float ff = (float)freq;
  float ang = (float)((double)p * (double)ff);
  cosT[idx] = (float)cos((double)ang);
  sinT[idx] = (float)sin((double)ang);
}

// ---------- GEMM: A[M,K] bf16 @ Bt[N,K] bf16 -> C[M,N] (bf16 or f32) ----------
template<int OUTF32>
__global__ __launch_bounds__(256)
void k_gemm_bt(const u16* __restrict__ A, const u16* __restrict__ Bt, void* __restrict__ Cout,
               int M, int N, int K){
  __shared__ __align__(16) u16 lsA[128*32];
  __shared__ __align__(16) u16 lsB[128*32];
  const int t = threadIdx.x;
  const int m0 = blockIdx.y*128, n0 = blockIdx.x*128;
  const int wv = t>>6, ln = t&63;
  const int wr = (wv>>1)*64, wc = (wv&1)*64;
  const int fr = ln&15, kh = (ln>>4)*8;
  const int srow = wv*16 + (ln>>2), sk = (ln&3)*8;
  const u16* Ag = A + (size_t)(m0 + srow)*K + sk;
  const u16* Bg = Bt + (size_t)(n0 + srow)*K + sk;
  u16* lA0 = &lsA[wv*512];
  u16* lB0 = &lsB[wv*512];
  floatx4 acc[4][4];
#pragma unroll
  for(int i=0;i<4;i++)
#pragma unroll
    for(int j=0;j<4;j++) acc[i][j] = (floatx4){0.f,0.f,0.f,0.f};
  for(int k0=0;k0<K;k0+=32){
    __syncthreads();
    gl_lds16(Ag + k0,              lA0);
    gl_lds16(Ag + (size_t)64*K + k0, lA0 + 2048);
    gl_lds16(Bg + k0,              lB0);
    gl_lds16(Bg + (size_t)64*K + k0, lB0 + 2048);
    __syncthreads();
    short8 af[4], bf[4];
#pragma unroll
    for(int i=0;i<4;i++) af[i] = *(const short8*)&lsA[(wr + i*16 + fr)*32 + kh];
#pragma unroll
    for(int i=0;i<4;i++) bf[i] = *(const short8*)&lsB[(wc + i*16 + fr)*32 + kh];
#pragma unroll
    for(int mi=0;mi<4;mi++)
#pragma unroll
      for(int ni=0;ni<4;ni++) acc[mi][ni] = mfma16(af[mi], bf[ni], acc[mi][ni]);
  }
  const int r0 = (ln>>4)*4, c0 = ln&15;
#pragma unroll
  for(int mi=0;mi<4;mi++)
#pragma unroll
    for(int ni=0;ni<4;ni++){
      const int row = m0 + wr + mi*16 + r0;
      const int col = n0 + wc + ni*16 + c0;
#pragma unroll
      for(int r=0;r<4;r++){
        float v = acc[mi][ni][r];
        if(OUTF32) ((float*)Cout)[(size_t)(row+r)*N + col] = v;
        else       ((u16*)Cout)[(size_t)(row+r)*N + col] = f2bf(v);
      }
    }
}

// ---------- layernorm(kv[:512]) -> bf16 ; rope(kv[512:640]) -> k_pe bf16 ----------
__global__ __launch_bounds__(256)
void k_ln_rope(const float* __restrict__ kv, const float* __restrict__ scale,
               const int* __restrict__ pid, const float* __restrict__ cosT,
               const float* __restrict__ sinT, u16* __restrict__ kv_cn, u16* __restrict__ k_pe){
  const int tok = blockIdx.x;
  const int t = threadIdx.x;
  const float* row = kv + (size_t)tok*640;
  float v0 = row[2*t], v1 = row[2*t+1];
  float s = v0+v1, ss = v0*v0+v1*v1;
#pragma unroll
  for(int off=32; off>=1; off>>=1){ s += __shfl_xor(s,off); ss += __shfl_xor(ss,off); }
  __shared__ float red[8];
  if((t&63)==0){ red[t>>6]=s; red[4+(t>>6)]=ss; }
  __syncthreads();
  float S4 = red[0]+red[1]+red[2]+red[3];
  float SS4 = red[4]+red[5]+red[6]+red[7];
  float mean = S4*(1.f/512.f);
  float var = SS4*(1.f/512.f) - mean*mean;
  float inv = rsqrtf(var + 1e-5f);
  kv_cn[(size_t)tok*512 + 2*t]   = f2bf((v0-mean)*inv*scale[2*t]);
  kv_cn[(size_t)tok*512 + 2*t+1] = f2bf((v1-mean)*inv*scale[2*t+1]);
  if(t < 128){
    const int sidx = tok & 2047;
    const int p = pid[sidx];
    const int i = t>>1;
    float c = cosT[p*64+i], sn = sinT[p*64+i];
    float xr = row[512+2*i], xi = row[512+2*i+1];
    float val = (t&1) ? (xr*sn + xi*c) : (xr*c - xi*sn);
    k_pe[(size_t)tok*128 + t] = f2bf(val);
  }
}

// ---------- q: copy nope, rope pe; fold scale*log2e; layout [B,H,S,256] ----------
__global__ __launch_bounds__(256)
void k_q_rope(const u16* __restrict__ q_raw, const int* __restrict__ pid,
              const float* __restrict__ cosT, const float* __restrict__ sinT,
              u16* __restrict__ q_fin){
  const float QS = (float)(0.08838834764831845 * 1.4426950408889634); // /sqrt(128) * log2(e)
  const int tok = blockIdx.x;
  const int b = tok>>11, sidx = tok&2047;
  const int t = threadIdx.x;
  const int p = pid[sidx];
  for(int h=0; h<16; h++){
    const u16* src = q_raw + (size_t)tok*4096 + h*256;
    float val;
    if(t < 128) val = bf2f(src[t]);
    else {
      int d = t-128, i = d>>1;
      float c = cosT[p*64+i], sn = sinT[p*64+i];
      float xr = bf2f(src[128+2*i]), xi = bf2f(src[128+2*i+1]);
      val = (d&1) ? (xr*sn + xi*c) : (xr*c - xi*sn);
    }
    q_fin[(((size_t)(b*16 + h))*2048 + sidx)*256 + t] = f2bf(val*QS);
  }
}

// ---------- k_full[b][kvh][s][256] = concat(k_nope, k_pe) ----------
__global__ __launch_bounds__(256)
void k_build_k(const u16* __restrict__ kvb, const u16* __restrict__ k_pe, u16* __restrict__ k_full){
  const int tok = blockIdx.x;
  const int b = tok>>11, sidx = tok&2047;
  const int t = threadIdx.x;
  for(int kh=0; kh<8; kh++){
    u16 v = (t<128) ? kvb[(size_t)tok*2048 + kh*256 + t]
                    : k_pe[(size_t)tok*128 + (t-128)];
    k_full[(((size_t)(b*8 + kh))*2048 + sidx)*256 + t] = v;
  }
}

// ---------- v_t[b][kvh][hd][s] from kvb v-part ----------
__global__ void k_v_t(const u16* __restrict__ kvb, u16* __restrict__ v_t){
  __shared__ u16 tile[32][33];
  const int sb = blockIdx.x*32, hb = blockIdx.y*32;
  const int bk = blockIdx.z;
  const int b = bk>>3, kh = bk&7;
  const int tx = threadIdx.x, ty = threadIdx.y;
#pragma unroll
  for(int i=0;i<4;i++){
    int sidx = sb + ty + i*8;
    tile[ty+i*8][tx] = kvb[((size_t)(b*2048 + sidx))*2048 + kh*256 + 128 + hb + tx];
  }
  __syncthreads();
#pragma unroll
  for(int i=0;i<4;i++){
    int hd = hb + ty + i*8;
    v_t[((size_t)bk*128 + hd)*2048 + sb + tx] = tile[tx][ty+i*8];
  }
}

// ---------- flash attention, S^T layout, no LDS K-staging ----------
// 1024 blocks, one 64-query tile each. Group g=(b*8+kvh) has 64 blocks
// (32 q-tiles x 2 heads); block id chosen so all of group g share
// (id % 8) -> same XCD under round-robin dispatch -> K/V stay L2-resident
// (~3 MB/XCD working set). Within a group, big q-tiles dispatch first.
// K and V fragments are read directly from global: tile is L1-resident and
// shared by the block's 4 waves (raw s_barrier keeps them in lockstep);
// per-group data is L2-resident. Only per-wave P lives in LDS (9 KB) ->
// 4 blocks/CU (16 waves/CU) vs previous 2 blocks/CU.
__global__ __launch_bounds__(256, 4)
void k_attn(const u16* __restrict__ q_fin, const u16* __restrict__ k_full,
            const u16* __restrict__ v_t, u16* __restrict__ attn){
  __shared__ __align__(16) u16 lsP[4*16*72];  // 9216 B per-block (per-wave P)
  // decode swizzled id: blk = (g>>3)*512 + i*8 + (g&7)
  const int blk = blockIdx.x;
  const int g  = (blk>>9)*8 + (blk&7);   // 0..15 = b*8+kvh
  const int i  = (blk>>3)&63;            // 0..63 within group
  const int b  = g>>3, kvh = g&7;
  const int qt = 31 - (i>>1);            // descending: big tiles first
  const int h  = kvh*2 + (i&1);
  const int t = threadIdx.x, wv = t>>6, ln = t&63;
  const int fq = ln&15, gq = ln>>4;
  const u16* kbase = k_full + ((size_t)(b*8 + kvh))*2048*256;
  const u16* vbase = v_t + ((size_t)(b*8 + kvh))*128*2048;
  u16* Pw = &lsP[wv*16*72];

  // Q fragments for this wave's 16 q rows (row = q, cols = 256 dims)
  short8 qf[8];
  const u16* qb = q_fin + (((size_t)(b*16 + h))*2048 + qt*64 + wv*16 + fq)*256;
#pragma unroll
  for(int c=0;c<8;c++) qf[c] = *(const short8*)(qb + c*32 + gq*8);

  floatx4 oacc[8];
#pragma unroll
  for(int ii=0;ii<8;ii++) oacc[ii] = (floatx4){0.f,0.f,0.f,0.f};
  float mprev = -3e38f, lsum = 0.f;

  // per-lane K row pointers (K fragment rows for ns sub-tiles)
  const u16* kp0 = kbase + (size_t)(fq)*256       + gq*8;
  const u16* kp1 = kbase + (size_t)(16 + fq)*256  + gq*8;
  const u16* kp2 = kbase + (size_t)(32 + fq)*256  + gq*8;
  const u16* kp3 = kbase + (size_t)(48 + fq)*256  + gq*8;
  const u16* vp  = vbase + (size_t)fq*2048 + gq*8;

  for(int kt=0; kt<=qt; kt++){
    __builtin_amdgcn_s_barrier();  // pacing only: keep 4 waves on same K/V tile (L1 reuse)
    const size_t ko = (size_t)kt*16384;   // 64 rows * 256 cols per tile

    // S^T = K · Q^T : rows kv, cols q  (K straight from global, L1/L2-hit)
    floatx4 sc[4];
#pragma unroll
    for(int ns=0;ns<4;ns++) sc[ns] = (floatx4){0.f,0.f,0.f,0.f};
    const u16* krp[4] = { kp0 + ko, kp1 + ko, kp2 + ko, kp3 + ko };
#pragma unroll
    for(int ns=0;ns<4;ns++){
#pragma unroll
      for(int c=0;c<8;c++){
        short8 kf = *(const short8*)(krp[ns] + c*32);
        sc[ns] = mfma16(kf, qf[c], sc[ns]);
      }
    }
    if(kt == qt){  // diagonal tile: mask kv > q
      const int qloc = wv*16 + fq;
#pragma unroll
      for(int ns=0;ns<4;ns++)
#pragma unroll
        for(int r=0;r<4;r++)
          if(ns*16 + gq*4 + r > qloc) sc[ns][r] = -1e30f;
    }
    // per-q (column) max
    float mloc = -3e38f;
#pragma unroll
    for(int ns=0;ns<4;ns++)
#pragma unroll
      for(int r=0;r<4;r++) mloc = fmaxf(mloc, sc[ns][r]);
    mloc = fmaxf(mloc, __shfl_xor(mloc, 16));
    mloc = fmaxf(mloc, __shfl_xor(mloc, 32));
    const float mn = fmaxf(mprev, mloc);
    const float alpha = exp2f(mprev - mn);
    float ps = 0.f;
#pragma unroll
    for(int ns=0;ns<4;ns++)
#pragma unroll
      for(int r=0;r<4;r++){
        float p = exp2f(sc[ns][r] - mn);
        sc[ns][r] = p;
        ps += p;
      }
    ps += __shfl_xor(ps, 16);
    ps += __shfl_xor(ps, 32);
    lsum = lsum*alpha + ps;
    mprev = mn;

    // P -> per-wave LDS in A-layout: row q=fq, cols kv
#pragma unroll
    for(int ns=0;ns<4;ns++){
      u32 p01 = (u32)f2bf(sc[ns][0]) | ((u32)f2bf(sc[ns][1])<<16);
      u32 p23 = (u32)f2bf(sc[ns][2]) | ((u32)f2bf(sc[ns][3])<<16);
      uint2 pk; pk.x = p01; pk.y = p23;
      *(uint2*)&Pw[fq*72 + ns*16 + gq*4] = pk;
    }
    // rescale O rows (row q = gq*4+r)
    float alphaO[4];
#pragma unroll
    for(int r=0;r<4;r++) alphaO[r] = __shfl(alpha, gq*4 + r);
#pragma unroll
    for(int hs=0;hs<8;hs++)
#pragma unroll
      for(int r=0;r<4;r++) oacc[hs][r] *= alphaO[r];
    __builtin_amdgcn_s_waitcnt(0xC07F);  // lgkmcnt(0): P visible to own wave

    // O += P · V  (V frags from global, L2-resident after swizzle)
#pragma unroll
    for(int cc=0;cc<2;cc++){
      short8 pa = *(const short8*)&Pw[fq*72 + cc*32 + gq*8];
#pragma unroll
      for(int hs=0;hs<8;hs++){
        short8 vb = *(const short8*)(vp + (size_t)hs*32768 + kt*64 + cc*32);
        oacc[hs] = mfma16(pa, vb, oacc[hs]);
      }
    }
  }
  const float inv = 1.f / lsum;
  float invO[4];
#pragma unroll
  for(int r=0;r<4;r++) invO[r] = __shfl(inv, gq*4 + r);
#pragma unroll
  for(int hs=0;hs<8;hs++)
#pragma unroll
    for(int r=0;r<4;r++){
      const int qi = qt*64 + wv*16 + gq*4 + r;
      attn[(((size_t)(b*2048 + qi))*16 + h)*128 + hs*16 + fq] = f2bf(oacc[hs][r]*invO[r]);
    }
}

extern "C" void kernel_launch(void* const* d_in, const int* in_sizes, int n_in,
                              void* d_out, int out_size, void* d_ws, size_t ws_size,
                              hipStream_t stream){
  const float* x    = (const float*)d_in[0];
  const float* wq   = (const float*)d_in[1];
  const float* wkva = (const float*)d_in[2];
  const float* kvsc = (const float*)d_in[3];
  const float* wkvb = (const float*)d_in[4];
  const float* wo   = (const float*)d_in[5];
  const int* pid  = (const int*)d_in[7];
  float* out = (float*)d_out;

  char* w = (char*)d_ws;
  size_t off = 0;
  auto alloc = [&](size_t bytes)->void*{
    void* p = (void*)(w + off);
    off += (bytes + 255) & ~(size_t)255;
    return p;
  };
  u16*   x_bf   = (u16*)alloc((size_t)4096*2048*2);
  u16*   wq_t   = (u16*)alloc((size_t)4096*2048*2);
  u16*   wkva_t = (u16*)alloc((size_t)640*2048*2);
  u16*   wkvb_t = (u16*)alloc((size_t)2048*512*2);
  u16*   wo_t   = (u16*)alloc((size_t)2048*2048*2);
  float* cosT   = (float*)alloc((size_t)2048*64*4);
  float* sinT   = (float*)alloc((size_t)2048*64*4);
  u16*   q_raw  = (u16*)alloc((size_t)4096*4096*2);
  float* kvf    = (float*)alloc((size_t)4096*640*4);
  u16*   kv_cn  = (u16*)alloc((size_t)4096*512*2);
  u16*   k_pe   = (u16*)alloc((size_t)4096*128*2);
  u16*   kvb    = (u16*)alloc((size_t)4096*2048*2);
  u16*   q_fin  = (u16*)alloc((size_t)4096*4096*2);
  u16*   k_full = (u16*)alloc((size_t)2*8*2048*256*2);
  u16*   v_t    = (u16*)alloc((size_t)2*8*128*2048*2);
  u16*   attn   = (u16*)alloc((size_t)4096*2048*2);

  k_f2b<<<8192, 256, 0, stream>>>(x, x_bf, (size_t)4096*2048);
  k_transpose<<<dim3(128, 64), dim3(32,8), 0, stream>>>(wq,   wq_t,   2048, 4096);
  k_transpose<<<dim3(20,  64), dim3(32,8), 0, stream>>>(wkva, wkva_t, 2048, 640);
  k_transpose<<<dim3(64,  16), dim3(32,8), 0, stream>>>(wkvb, wkvb_t, 512,  2048);
  k_transpose<<<dim3(64,  64), dim3(32,8), 0, stream>>>(wo,   wo_t,   2048, 2048);
  k_rope_table<<<512, 256, 0, stream>>>(cosT, sinT);

  k_gemm_bt<0><<<dim3(32, 32), 256, 0, stream>>>(x_bf, wq_t, q_raw, 4096, 4096, 2048);
  k_gemm_bt<1><<<dim3(5,  32), 256, 0, stream>>>(x_bf, wkva_t, kvf, 4096, 640, 2048);
  k_ln_rope<<<4096, 256, 0, stream>>>(kvf, kvsc, pid, cosT, sinT, kv_cn, k_pe);
  k_gemm_bt<0><<<dim3(16, 32), 256, 0, stream>>>(kv_cn, wkvb_t, kvb, 4096, 2048, 512);
  k_q_rope<<<4096, 256, 0, stream>>>(q_raw, pid, cosT, sinT, q_fin);
  k_build_k<<<4096, 256, 0, stream>>>(kvb, k_pe, k_full);
  k_v_t<<<dim3(64, 4, 16), dim3(32,8), 0, stream>>>(kvb, v_t);
  k_attn<<<1024, 256, 0, stream>>>(q_fin, k_full, v_t, attn);
  k_gemm_bt<1><<<dim3(16, 32), 256, 0, stream>>>(attn, wo_t, out, 4096, 2048, 2048);
}

// Round 2
// 592.243 us; speedup vs baseline: 1.5864x; 1.5864x over previous
//
#include <hip/hip_runtime.h>

// MLA forward. Inputs f32, internal bf16 MFMA 16x16x32, output f32.
// R9: revert R8 (global-direct K + forced occupancy spilled -> 546us).
// Back to R7 structure (512 blocks, 64-q tile, 2 halves, LDS K tile), with
// ONE change: 2-phase double-buffered K staging via global_load_lds(16B).
// - K tiles 2x 64x256 linear LDS, XOR-swizzle (byte ^= (row&7)<<4) applied on
//   the per-lane GLOBAL source address (dest must be linear for gl_lds) and on
//   the ds_read side -> conflict-free-profile reads, zero staging write traffic
//   through VGPRs, no LDS write conflicts.
// - stage(tile kt+1) issued BEFORE compute(tile kt); single __syncthreads()
//   per iteration AFTER compute (drain overlaps with QK+softmax+PV).

typedef __attribute__((ext_vector_type(8))) short short8;
typedef __attribute__((ext_vector_type(4))) float floatx4;
typedef unsigned short u16;
typedef unsigned int u32;

__device__ __forceinline__ float bf2f(u16 u){ u32 x=((u32)u)<<16; return __builtin_bit_cast(float,x); }
__device__ __forceinline__ u16 f2bf(float f){ u32 x=__builtin_bit_cast(u32,f); return (u16)((x + 0x7fffu + ((x>>16)&1u))>>16); }

__device__ __forceinline__ floatx4 mfma16(short8 a, short8 b, floatx4 c){
  return __builtin_amdgcn_mfma_f32_16x16x32_bf16(a,b,c,0,0,0);
}

// async global->LDS, 16B per lane. LDS dest = wave-uniform base + lane*16.
__device__ __forceinline__ void gl_lds16(const u16* g, u16* l){
  __builtin_amdgcn_global_load_lds((const __attribute__((address_space(1))) void*)g,
                                   (__attribute__((address_space(3))) void*)l, 16, 0, 0);
}

// ---------- f32 -> bf16 elementwise (for x) ----------
__global__ __launch_bounds__(256)
void k_f2b(const float* __restrict__ in, u16* __restrict__ out, size_t n){
  size_t i = ((size_t)blockIdx.x*256 + threadIdx.x)*4;
  if(i >= n) return;
  float4 v = *(const float4*)(in + i);
  out[i+0] = f2bf(v.x); out[i+1] = f2bf(v.y); out[i+2] = f2bf(v.z); out[i+3] = f2bf(v.w);
}

// ---------- transpose + convert: f32 [K,N] -> bf16 [N,K] ----------
__global__ void k_transpose(const float* __restrict__ in, u16* __restrict__ out, int K, int N){
  __shared__ u16 tile[32][33];
  const int kb = blockIdx.y*32, nb = blockIdx.x*32;
  const int tx = threadIdx.x, ty = threadIdx.y;
#pragma unroll
  for(int i=0;i<4;i++) tile[ty+i*8][tx] = f2bf(in[(size_t)(kb+ty+i*8)*N + nb + tx]);
  __syncthreads();
#pragma unroll
  for(int i=0;i<4;i++) out[(size_t)(nb+ty+i*8)*K + kb + tx] = tile[tx][ty+i*8];
}

// ---------- rope table (fp64 for large-angle accuracy) ----------
__global__ void k_rope_table(float* __restrict__ cosT, float* __restrict__ sinT){
  int idx = blockIdx.x*256 + threadIdx.x;
  if(idx >= 2048*64) return;
  int p = idx>>6, i = idx&63;
  double freq = pow(10000.0, -(double)(2*i)/128.0) * 40.0;
  float ff = (float)freq;
  float ang = (float)((double)p * (double)ff);
  cosT[idx] = (float)cos((double)ang);
  sinT[idx] = (float)sin((double)ang);
}

// ---------- GEMM: A[M,K] bf16 @ Bt[N,K] bf16 -> C[M,N] (bf16 or f32) ----------
template<int OUTF32>
__global__ __launch_bounds__(256)
void k_gemm_bt(const u16* __restrict__ A, const u16* __restrict__ Bt, void* __restrict__ Cout,
               int M, int N, int K){
  __shared__ __align__(16) u16 lsA[128*32];
  __shared__ __align__(16) u16 lsB[128*32];
  const int t = threadIdx.x;
  const int m0 = blockIdx.y*128, n0 = blockIdx.x*128;
  const int wv = t>>6, ln = t&63;
  const int wr = (wv>>1)*64, wc = (wv&1)*64;
  const int fr = ln&15, kh = (ln>>4)*8;
  const int srow = wv*16 + (ln>>2), sk = (ln&3)*8;
  const u16* Ag = A + (size_t)(m0 + srow)*K + sk;
  const u16* Bg = Bt + (size_t)(n0 + srow)*K + sk;
  u16* lA0 = &lsA[wv*512];
  u16* lB0 = &lsB[wv*512];
  floatx4 acc[4][4];
#pragma unroll
  for(int i=0;i<4;i++)
#pragma unroll
    for(int j=0;j<4;j++) acc[i][j] = (floatx4){0.f,0.f,0.f,0.f};
  for(int k0=0;k0<K;k0+=32){
    __syncthreads();
    gl_lds16(Ag + k0,              lA0);
    gl_lds16(Ag + (size_t)64*K + k0, lA0 + 2048);
    gl_lds16(Bg + k0,              lB0);
    gl_lds16(Bg + (size_t)64*K + k0, lB0 + 2048);
    __syncthreads();
    short8 af[4], bf[4];
#pragma unroll
    for(int i=0;i<4;i++) af[i] = *(const short8*)&lsA[(wr + i*16 + fr)*32 + kh];
#pragma unroll
    for(int i=0;i<4;i++) bf[i] = *(const short8*)&lsB[(wc + i*16 + fr)*32 + kh];
#pragma unroll
    for(int mi=0;mi<4;mi++)
#pragma unroll
      for(int ni=0;ni<4;ni++) acc[mi][ni] = mfma16(af[mi], bf[ni], acc[mi][ni]);
  }
  const int r0 = (ln>>4)*4, c0 = ln&15;
#pragma unroll
  for(int mi=0;mi<4;mi++)
#pragma unroll
    for(int ni=0;ni<4;ni++){
      const int row = m0 + wr + mi*16 + r0;
      const int col = n0 + wc + ni*16 + c0;
#pragma unroll
      for(int r=0;r<4;r++){
        float v = acc[mi][ni][r];
        if(OUTF32) ((float*)Cout)[(size_t)(row+r)*N + col] = v;
        else       ((u16*)Cout)[(size_t)(row+r)*N + col] = f2bf(v);
      }
    }
}

// ---------- layernorm(kv[:512]) -> bf16 ; rope(kv[512:640]) -> k_pe bf16 ----------
__global__ __launch_bounds__(256)
void k_ln_rope(const float* __restrict__ kv, const float* __restrict__ scale,
               const int* __restrict__ pid, const float* __restrict__ cosT,
               const float* __restrict__ sinT, u16* __restrict__ kv_cn, u16* __restrict__ k_pe){
  const int tok = blockIdx.x;
  const int t = threadIdx.x;
  const float* row = kv + (size_t)tok*640;
  float v0 = row[2*t], v1 = row[2*t+1];
  float s = v0+v1, ss = v0*v0+v1*v1;
#pragma unroll
  for(int off=32; off>=1; off>>=1){ s += __shfl_xor(s,off); ss += __shfl_xor(ss,off); }
  __shared__ float red[8];
  if((t&63)==0){ red[t>>6]=s; red[4+(t>>6)]=ss; }
  __syncthreads();
  float S4 = red[0]+red[1]+red[2]+red[3];
  float SS4 = red[4]+red[5]+red[6]+red[7];
  float mean = S4*(1.f/512.f);
  float var = SS4*(1.f/512.f) - mean*mean;
  float inv = rsqrtf(var + 1e-5f);
  kv_cn[(size_t)tok*512 + 2*t]   = f2bf((v0-mean)*inv*scale[2*t]);
  kv_cn[(size_t)tok*512 + 2*t+1] = f2bf((v1-mean)*inv*scale[2*t+1]);
  if(t < 128){
    const int sidx = tok & 2047;
    const int p = pid[sidx];
    const int i = t>>1;
    float c = cosT[p*64+i], sn = sinT[p*64+i];
    float xr = row[512+2*i], xi = row[512+2*i+1];
    float val = (t&1) ? (xr*sn + xi*c) : (xr*c - xi*sn);
    k_pe[(size_t)tok*128 + t] = f2bf(val);
  }
}

// ---------- q: copy nope, rope pe; fold scale*log2e; layout [B,H,S,256] ----------
__global__ __launch_bounds__(256)
void k_q_rope(const u16* __restrict__ q_raw, const int* __restrict__ pid,
              const float* __restrict__ cosT, const float* __restrict__ sinT,
              u16* __restrict__ q_fin){
  const float QS = (float)(0.08838834764831845 * 1.4426950408889634); // /sqrt(128) * log2(e)
  const int tok = blockIdx.x;
  const int b = tok>>11, sidx = tok&2047;
  const int t = threadIdx.x;
  const int p = pid[sidx];
  for(int h=0; h<16; h++){
    const u16* src = q_raw + (size_t)tok*4096 + h*256;
    float val;
    if(t < 128) val = bf2f(src[t]);
    else {
      int d = t-128, i = d>>1;
      float c = cosT[p*64+i], sn = sinT[p*64+i];
      float xr = bf2f(src[128+2*i]), xi = bf2f(src[128+2*i+1]);
      val = (d&1) ? (xr*sn + xi*c) : (xr*c - xi*sn);
    }
    q_fin[(((size_t)(b*16 + h))*2048 + sidx)*256 + t] = f2bf(val*QS);
  }
}

// ---------- k_full[b][kvh][s][256] = concat(k_nope, k_pe) ----------
__global__ __launch_bounds__(256)
void k_build_k(const u16* __restrict__ kvb, const u16* __restrict__ k_pe, u16* __restrict__ k_full){
  const int tok = blockIdx.x;
  const int b = tok>>11, sidx = tok&2047;
  const int t = threadIdx.x;
  for(int kh=0; kh<8; kh++){
    u16 v = (t<128) ? kvb[(size_t)tok*2048 + kh*256 + t]
                    : k_pe[(size_t)tok*128 + (t-128)];
    k_full[(((size_t)(b*8 + kh))*2048 + sidx)*256 + t] = v;
  }
}

// ---------- v_t[b][kvh][hd][s] from kvb v-part ----------
__global__ void k_v_t(const u16* __restrict__ kvb, u16* __restrict__ v_t){
  __shared__ u16 tile[32][33];
  const int sb = blockIdx.x*32, hb = blockIdx.y*32;
  const int bk = blockIdx.z;
  const int b = bk>>3, kh = bk&7;
  const int tx = threadIdx.x, ty = threadIdx.y;
#pragma unroll
  for(int i=0;i<4;i++){
    int sidx = sb + ty + i*8;
    tile[ty+i*8][tx] = kvb[((size_t)(b*2048 + sidx))*2048 + kh*256 + 128 + hb + tx];
  }
  __syncthreads();
#pragma unroll
  for(int i=0;i<4;i++){
    int hd = hb + ty + i*8;
    v_t[((size_t)bk*128 + hd)*2048 + sb + tx] = tile[tx][ty+i*8];
  }
}

// ---------- flash attention, S^T layout, XCD-swizzled 1D grid ----------
// 512 blocks. Group g=(b*8+kvh) has 32 blocks (16 pr x 2 heads); block id
// chosen so all of group g share (id % 8) -> same XCD under round-robin
// dispatch -> K/V stay L2-resident (4 MB/XCD working set).
// K staging: 2-phase double-buffered linear 64x256 LDS tiles via
// global_load_lds(16B); XOR col swizzle (byte ^= (row&7)<<4) applied on the
// per-lane global source address and on ds_read addresses.
__global__ __launch_bounds__(256)
void k_attn(const u16* __restrict__ q_fin, const u16* __restrict__ k_full,
            const u16* __restrict__ v_t, u16* __restrict__ attn){
  __shared__ __align__(16) u16 lsK[2*16384];  // 2 x 32 KiB K tiles (linear, swizzled)
  __shared__ __align__(16) u16 lsP[4*16*72];  // 9216 B per-wave P
  // decode swizzled id: blk = hi*256 + i*8 + (g&7), hi = g>>3
  const int blk = blockIdx.x;
  const int g  = (blk>>8)*8 + (blk&7);   // 0..15 = b*8+kvh
  const int i  = (blk>>3)&31;            // 0..31 within group
  const int b  = g>>3, kvh = g&7;
  const int pr = i&15;
  const int h  = kvh*2 + (i>>4);
  const int t = threadIdx.x, wv = t>>6, ln = t&63;
  const int fq = ln&15, gq = ln>>4;
  const u16* kbase = k_full + ((size_t)(b*8 + kvh))*2048*256;
  const u16* vbase = v_t + ((size_t)(b*8 + kvh))*128*2048;
  u16* Pw = &lsP[wv*16*72];

  // staging: per-lane swizzled global byte offsets within a 32 KiB K tile.
  // thread covers LDS bytes o = s8*4096 + wv*1024 + ln*16 (linear dest);
  // source element = (row = o>>9, col = (o&511) ^ ((row&7)<<4)).
  int soff[8];
#pragma unroll
  for(int s8=0;s8<8;s8++){
    int o = s8*4096 + wv*1024 + ln*16;
    int row = o>>9, colb = o&511;
    soff[s8] = row*512 + (colb ^ ((row&7)<<4));
  }
  // QK-read swizzled column byte offsets (loop-invariant per lane)
  const int swz = (fq&7)<<4;
  int cb[8];
#pragma unroll
  for(int c=0;c<8;c++) cb[c] = (gq*16 + c*64) ^ swz;
  const int rowb = fq*512;

  for(int half=0; half<2; half++){
    const int qt = half ? (31-pr) : pr;
    short8 qf[8];
    const u16* qb = q_fin + (((size_t)(b*16 + h))*2048 + qt*64 + wv*16 + fq)*256;
#pragma unroll
    for(int c=0;c<8;c++) qf[c] = *(const short8*)(qb + c*32 + gq*8);
    floatx4 oacc[8];
#pragma unroll
    for(int ii=0;ii<8;ii++) oacc[ii] = (floatx4){0.f,0.f,0.f,0.f};
    float mprev = -3e38f, lsum = 0.f;

    // prologue: stage tile 0 into buffer 0
    {
      const char* ktile = (const char*)kbase;
#pragma unroll
      for(int s8=0;s8<8;s8++)
        gl_lds16((const u16*)(ktile + soff[s8]), &lsK[s8*2048 + wv*512]);
    }
    __syncthreads();   // drains gl_lds (compiler emits vmcnt(0) before barrier)

    int cur = 0;
    for(int kt=0; kt<=qt; kt++){
      // issue next tile's stage into the other buffer (flies under compute)
      if(kt < qt){
        const char* ktile = (const char*)kbase + (size_t)(kt+1)*32768;
        u16* dst = &lsK[(cur^1)*16384];
#pragma unroll
        for(int s8=0;s8<8;s8++)
          gl_lds16((const u16*)(ktile + soff[s8]), dst + s8*2048 + wv*512);
      }
      const char* Kc = (const char*)lsK + cur*32768;

      // S^T = K · Q^T : rows kv, cols q
      floatx4 sc[4];
#pragma unroll
      for(int ns=0;ns<4;ns++) sc[ns] = (floatx4){0.f,0.f,0.f,0.f};
#pragma unroll
      for(int ns=0;ns<4;ns++){
#pragma unroll
        for(int c=0;c<8;c++){
          short8 kf = *(const short8*)(Kc + ns*8192 + rowb + cb[c]);
          sc[ns] = mfma16(kf, qf[c], sc[ns]);
        }
      }
      if(kt == qt){  // diagonal tile: mask kv > q
        const int qloc = wv*16 + fq;
#pragma unroll
        for(int ns=0;ns<4;ns++)
#pragma unroll
          for(int r=0;r<4;r++)
            if(ns*16 + gq*4 + r > qloc) sc[ns][r] = -1e30f;
      }
      // per-q (column) max
      float mloc = -3e38f;
#pragma unroll
      for(int ns=0;ns<4;ns++)
#pragma unroll
        for(int r=0;r<4;r++) mloc = fmaxf(mloc, sc[ns][r]);
      mloc = fmaxf(mloc, __shfl_xor(mloc, 16));
      mloc = fmaxf(mloc, __shfl_xor(mloc, 32));
      const float mn = fmaxf(mprev, mloc);
      const float alpha = exp2f(mprev - mn);
      float ps = 0.f;
#pragma unroll
      for(int ns=0;ns<4;ns++)
#pragma unroll
        for(int r=0;r<4;r++){
          float p = exp2f(sc[ns][r] - mn);
          sc[ns][r] = p;
          ps += p;
        }
      ps += __shfl_xor(ps, 16);
      ps += __shfl_xor(ps, 32);
      lsum = lsum*alpha + ps;
      mprev = mn;

      // P -> per-wave LDS in A-layout: row q=fq, cols kv
#pragma unroll
      for(int ns=0;ns<4;ns++){
        u32 p01 = (u32)f2bf(sc[ns][0]) | ((u32)f2bf(sc[ns][1])<<16);
        u32 p23 = (u32)f2bf(sc[ns][2]) | ((u32)f2bf(sc[ns][3])<<16);
        uint2 pk; pk.x = p01; pk.y = p23;
        *(uint2*)&Pw[fq*72 + ns*16 + gq*4] = pk;
      }
      // rescale O rows (row q = gq*4+r)
      float alphaO[4];
#pragma unroll
      for(int r=0;r<4;r++) alphaO[r] = __shfl(alpha, gq*4 + r);
#pragma unroll
      for(int hs=0;hs<8;hs++)
#pragma unroll
        for(int r=0;r<4;r++) oacc[hs][r] *= alphaO[r];
      __builtin_amdgcn_s_waitcnt(0xC07F);  // lgkmcnt(0): P visible to own wave

      // O += P · V  (V frags from global, L2-resident after swizzle)
#pragma unroll
      for(int cc=0;cc<2;cc++){
        short8 pa = *(const short8*)&Pw[fq*72 + cc*32 + gq*8];
#pragma unroll
        for(int hs=0;hs<8;hs++){
          short8 vb = *(const short8*)(vbase + (size_t)(hs*16 + fq)*2048 + kt*64 + cc*32 + gq*8);
          oacc[hs] = mfma16(pa, vb, oacc[hs]);
        }
      }
      __syncthreads();   // end-of-iter: drains next-tile stage (overlapped) + syncs buffers
      cur ^= 1;
    }
    const float inv = 1.f / lsum;
    float invO[4];
#pragma unroll
    for(int r=0;r<4;r++) invO[r] = __shfl(inv, gq*4 + r);
#pragma unroll
    for(int hs=0;hs<8;hs++)
#pragma unroll
      for(int r=0;r<4;r++){
        const int qi = qt*64 + wv*16 + gq*4 + r;
        attn[(((size_t)(b*2048 + qi))*16 + h)*128 + hs*16 + fq] = f2bf(oacc[hs][r]*invO[r]);
      }
  }
}

extern "C" void kernel_launch(void* const* d_in, const int* in_sizes, int n_in,
                              void* d_out, int out_size, void* d_ws, size_t ws_size,
                              hipStream_t stream){
  const float* x    = (const float*)d_in[0];
  const float* wq   = (const float*)d_in[1];
  const float* wkva = (const float*)d_in[2];
  const float* kvsc = (const float*)d_in[3];
  const float* wkvb = (const float*)d_in[4];
  const float* wo   = (const float*)d_in[5];
  const int* pid  = (const int*)d_in[7];
  float* out = (float*)d_out;

  char* w = (char*)d_ws;
  size_t off = 0;
  auto alloc = [&](size_t bytes)->void*{
    void* p = (void*)(w + off);
    off += (bytes + 255) & ~(size_t)255;
    return p;
  };
  u16*   x_bf   = (u16*)alloc((size_t)4096*2048*2);
  u16*   wq_t   = (u16*)alloc((size_t)4096*2048*2);
  u16*   wkva_t = (u16*)alloc((size_t)640*2048*2);
  u16*   wkvb_t = (u16*)alloc((size_t)2048*512*2);
  u16*   wo_t   = (u16*)alloc((size_t)2048*2048*2);
  float* cosT   = (float*)alloc((size_t)2048*64*4);
  float* sinT   = (float*)alloc((size_t)2048*64*4);
  u16*   q_raw  = (u16*)alloc((size_t)4096*4096*2);
  float* kvf    = (float*)alloc((size_t)4096*640*4);
  u16*   kv_cn  = (u16*)alloc((size_t)4096*512*2);
  u16*   k_pe   = (u16*)alloc((size_t)4096*128*2);
  u16*   kvb    = (u16*)alloc((size_t)4096*2048*2);
  u16*   q_fin  = (u16*)alloc((size_t)4096*4096*2);
  u16*   k_full = (u16*)alloc((size_t)2*8*2048*256*2);
  u16*   v_t    = (u16*)alloc((size_t)2*8*128*2048*2);
  u16*   attn   = (u16*)alloc((size_t)4096*2048*2);

  k_f2b<<<8192, 256, 0, stream>>>(x, x_bf, (size_t)4096*2048);
  k_transpose<<<dim3(128, 64), dim3(32,8), 0, stream>>>(wq,   wq_t,   2048, 4096);
  k_transpose<<<dim3(20,  64), dim3(32,8), 0, stream>>>(wkva, wkva_t, 2048, 640);
  k_transpose<<<dim3(64,  16), dim3(32,8), 0, stream>>>(wkvb, wkvb_t, 512,  2048);
  k_transpose<<<dim3(64,  64), dim3(32,8), 0, stream>>>(wo,   wo_t,   2048, 2048);
  k_rope_table<<<512, 256, 0, stream>>>(cosT, sinT);

  k_gemm_bt<0><<<dim3(32, 32), 256, 0, stream>>>(x_bf, wq_t, q_raw, 4096, 4096, 2048);
  k_gemm_bt<1><<<dim3(5,  32), 256, 0, stream>>>(x_bf, wkva_t, kvf, 4096, 640, 2048);
  k_ln_rope<<<4096, 256, 0, stream>>>(kvf, kvsc, pid, cosT, sinT, kv_cn, k_pe);
  k_gemm_bt<0><<<dim3(16, 32), 256, 0, stream>>>(kv_cn, wkvb_t, kvb, 4096, 2048, 512);
  k_q_rope<<<4096, 256, 0, stream>>>(q_raw, pid, cosT, sinT, q_fin);
  k_build_k<<<4096, 256, 0, stream>>>(kvb, k_pe, k_full);
  k_v_t<<<dim3(64, 4, 16), dim3(32,8), 0, stream>>>(kvb, v_t);
  k_attn<<<512, 256, 0, stream>>>(q_fin, k_full, v_t, attn);
  k_gemm_bt<1><<<dim3(16, 32), 256, 0, stream>>>(attn, wo_t, out, 4096, 2048, 2048);
}

// Round 3
// 525.722 us; speedup vs baseline: 1.7872x; 1.1265x over previous
//
#include <hip/hip_runtime.h>

// MLA forward. Inputs f32, internal bf16 MFMA 16x16x32, output f32.
// R10: attack V-read L1 scatter (16 lines per load instr, 2k cyc/iter/CU).
// - v_t is now TILE-MAJOR [b][kvh][kt(64 tiles)][hd=128][kv=32]; per-iter V
//   tile (8KB) is contiguous -> reg-staged coalesced (32B/thread) into padded
//   LDS [128][40] (double-buffered), T14 split: load at top, ds_write after PV.
// - KVBLK 64->32 so K(2x16KB,gl_lds+XOR-src-swizzle) + V(2x10KB) + P(5KB)
//   = 57KB -> keeps 2 blocks/CU.
// - k_q_rope / k_build_k vectorized to short8 (were scalar u16 over ~100MB).

typedef __attribute__((ext_vector_type(8))) short short8;
typedef __attribute__((ext_vector_type(4))) float floatx4;
typedef unsigned short u16;
typedef unsigned int u32;

__device__ __forceinline__ float bf2f(u16 u){ u32 x=((u32)u)<<16; return __builtin_bit_cast(float,x); }
__device__ __forceinline__ u16 f2bf(float f){ u32 x=__builtin_bit_cast(u32,f); return (u16)((x + 0x7fffu + ((x>>16)&1u))>>16); }

__device__ __forceinline__ floatx4 mfma16(short8 a, short8 b, floatx4 c){
  return __builtin_amdgcn_mfma_f32_16x16x32_bf16(a,b,c,0,0,0);
}

// async global->LDS, 16B per lane. LDS dest = wave-uniform base + lane*16.
__device__ __forceinline__ void gl_lds16(const u16* g, u16* l){
  __builtin_amdgcn_global_load_lds((const __attribute__((address_space(1))) void*)g,
                                   (__attribute__((address_space(3))) void*)l, 16, 0, 0);
}

// ---------- f32 -> bf16 elementwise (for x) ----------
__global__ __launch_bounds__(256)
void k_f2b(const float* __restrict__ in, u16* __restrict__ out, size_t n){
  size_t i = ((size_t)blockIdx.x*256 + threadIdx.x)*4;
  if(i >= n) return;
  float4 v = *(const float4*)(in + i);
  out[i+0] = f2bf(v.x); out[i+1] = f2bf(v.y); out[i+2] = f2bf(v.z); out[i+3] = f2bf(v.w);
}

// ---------- transpose + convert: f32 [K,N] -> bf16 [N,K] ----------
__global__ void k_transpose(const float* __restrict__ in, u16* __restrict__ out, int K, int N){
  __shared__ u16 tile[32][33];
  const int kb = blockIdx.y*32, nb = blockIdx.x*32;
  const int tx = threadIdx.x, ty = threadIdx.y;
#pragma unroll
  for(int i=0;i<4;i++) tile[ty+i*8][tx] = f2bf(in[(size_t)(kb+ty+i*8)*N + nb + tx]);
  __syncthreads();
#pragma unroll
  for(int i=0;i<4;i++) out[(size_t)(nb+ty+i*8)*K + kb + tx] = tile[tx][ty+i*8];
}

// ---------- rope table (fp64 for large-angle accuracy) ----------
__global__ void k_rope_table(float* __restrict__ cosT, float* __restrict__ sinT){
  int idx = blockIdx.x*256 + threadIdx.x;
  if(idx >= 2048*64) return;
  int p = idx>>6, i = idx&63;
  double freq = pow(10000.0, -(double)(2*i)/128.0) * 40.0;
  float ff = (float)freq;
  float ang = (float)((double)p * (double)ff);
  cosT[idx] = (float)cos((double)ang);
  sinT[idx] = (float)sin((double)ang);
}

// ---------- GEMM: A[M,K] bf16 @ Bt[N,K] bf16 -> C[M,N] (bf16 or f32) ----------
template<int OUTF32>
__global__ __launch_bounds__(256)
void k_gemm_bt(const u16* __restrict__ A, const u16* __restrict__ Bt, void* __restrict__ Cout,
               int M, int N, int K){
  __shared__ __align__(16) u16 lsA[128*32];
  __shared__ __align__(16) u16 lsB[128*32];
  const int t = threadIdx.x;
  const int m0 = blockIdx.y*128, n0 = blockIdx.x*128;
  const int wv = t>>6, ln = t&63;
  const int wr = (wv>>1)*64, wc = (wv&1)*64;
  const int fr = ln&15, kh = (ln>>4)*8;
  const int srow = wv*16 + (ln>>2), sk = (ln&3)*8;
  const u16* Ag = A + (size_t)(m0 + srow)*K + sk;
  const u16* Bg = Bt + (size_t)(n0 + srow)*K + sk;
  u16* lA0 = &lsA[wv*512];
  u16* lB0 = &lsB[wv*512];
  floatx4 acc[4][4];
#pragma unroll
  for(int i=0;i<4;i++)
#pragma unroll
    for(int j=0;j<4;j++) acc[i][j] = (floatx4){0.f,0.f,0.f,0.f};
  for(int k0=0;k0<K;k0+=32){
    __syncthreads();
    gl_lds16(Ag + k0,              lA0);
    gl_lds16(Ag + (size_t)64*K + k0, lA0 + 2048);
    gl_lds16(Bg + k0,              lB0);
    gl_lds16(Bg + (size_t)64*K + k0, lB0 + 2048);
    __syncthreads();
    short8 af[4], bf[4];
#pragma unroll
    for(int i=0;i<4;i++) af[i] = *(const short8*)&lsA[(wr + i*16 + fr)*32 + kh];
#pragma unroll
    for(int i=0;i<4;i++) bf[i] = *(const short8*)&lsB[(wc + i*16 + fr)*32 + kh];
#pragma unroll
    for(int mi=0;mi<4;mi++)
#pragma unroll
      for(int ni=0;ni<4;ni++) acc[mi][ni] = mfma16(af[mi], bf[ni], acc[mi][ni]);
  }
  const int r0 = (ln>>4)*4, c0 = ln&15;
#pragma unroll
  for(int mi=0;mi<4;mi++)
#pragma unroll
    for(int ni=0;ni<4;ni++){
      const int row = m0 + wr + mi*16 + r0;
      const int col = n0 + wc + ni*16 + c0;
#pragma unroll
      for(int r=0;r<4;r++){
        float v = acc[mi][ni][r];
        if(OUTF32) ((float*)Cout)[(size_t)(row+r)*N + col] = v;
        else       ((u16*)Cout)[(size_t)(row+r)*N + col] = f2bf(v);
      }
    }
}

// ---------- layernorm(kv[:512]) -> bf16 ; rope(kv[512:640]) -> k_pe bf16 ----------
__global__ __launch_bounds__(256)
void k_ln_rope(const float* __restrict__ kv, const float* __restrict__ scale,
               const int* __restrict__ pid, const float* __restrict__ cosT,
               const float* __restrict__ sinT, u16* __restrict__ kv_cn, u16* __restrict__ k_pe){
  const int tok = blockIdx.x;
  const int t = threadIdx.x;
  const float* row = kv + (size_t)tok*640;
  float v0 = row[2*t], v1 = row[2*t+1];
  float s = v0+v1, ss = v0*v0+v1*v1;
#pragma unroll
  for(int off=32; off>=1; off>>=1){ s += __shfl_xor(s,off); ss += __shfl_xor(ss,off); }
  __shared__ float red[8];
  if((t&63)==0){ red[t>>6]=s; red[4+(t>>6)]=ss; }
  __syncthreads();
  float S4 = red[0]+red[1]+red[2]+red[3];
  float SS4 = red[4]+red[5]+red[6]+red[7];
  float mean = S4*(1.f/512.f);
  float var = SS4*(1.f/512.f) - mean*mean;
  float inv = rsqrtf(var + 1e-5f);
  kv_cn[(size_t)tok*512 + 2*t]   = f2bf((v0-mean)*inv*scale[2*t]);
  kv_cn[(size_t)tok*512 + 2*t+1] = f2bf((v1-mean)*inv*scale[2*t+1]);
  if(t < 128){
    const int sidx = tok & 2047;
    const int p = pid[sidx];
    const int i = t>>1;
    float c = cosT[p*64+i], sn = sinT[p*64+i];
    float xr = row[512+2*i], xi = row[512+2*i+1];
    float val = (t&1) ? (xr*sn + xi*c) : (xr*c - xi*sn);
    k_pe[(size_t)tok*128 + t] = f2bf(val);
  }
}

// ---------- q: copy nope, rope pe; fold scale*log2e; layout [B,H,S,256] ----------
// vectorized: thread t handles head h=t>>4, 16 elems at seg*16 (short8 x2)
__global__ __launch_bounds__(256)
void k_q_rope(const u16* __restrict__ q_raw, const int* __restrict__ pid,
              const float* __restrict__ cosT, const float* __restrict__ sinT,
              u16* __restrict__ q_fin){
  const float QS = (float)(0.08838834764831845 * 1.4426950408889634); // /sqrt(128) * log2(e)
  const int tok = blockIdx.x;
  const int b = tok>>11, sidx = tok&2047;
  const int t = threadIdx.x;
  const int p = pid[sidx];
  const int h = t>>4, seg = t&15;
  const u16* src = q_raw + (size_t)tok*4096 + h*256 + seg*16;
  u16* dst = q_fin + (((size_t)(b*16 + h))*2048 + sidx)*256 + seg*16;
  short8 a = *(const short8*)src;
  short8 bv = *(const short8*)(src+8);
  short8 oa, ob;
  if(seg < 8){
#pragma unroll
    for(int j=0;j<8;j++){
      oa[j] = (short)f2bf(bf2f((u16)a[j])*QS);
      ob[j] = (short)f2bf(bf2f((u16)bv[j])*QS);
    }
  } else {
    const int i0 = seg*8 - 64;   // pair index base within 64 rope pairs
#pragma unroll
    for(int j=0;j<4;j++){
      float c = cosT[p*64 + i0 + j], sn = sinT[p*64 + i0 + j];
      float xr = bf2f((u16)a[2*j]), xi = bf2f((u16)a[2*j+1]);
      oa[2*j]   = (short)f2bf((xr*c - xi*sn)*QS);
      oa[2*j+1] = (short)f2bf((xr*sn + xi*c)*QS);
    }
#pragma unroll
    for(int j=0;j<4;j++){
      float c = cosT[p*64 + i0 + 4 + j], sn = sinT[p*64 + i0 + 4 + j];
      float xr = bf2f((u16)bv[2*j]), xi = bf2f((u16)bv[2*j+1]);
      ob[2*j]   = (short)f2bf((xr*c - xi*sn)*QS);
      ob[2*j+1] = (short)f2bf((xr*sn + xi*c)*QS);
    }
  }
  *(short8*)dst = oa;
  *(short8*)(dst+8) = ob;
}

// ---------- k_full[b][kvh][s][256] = concat(k_nope, k_pe), vectorized ----------
__global__ __launch_bounds__(256)
void k_build_k(const u16* __restrict__ kvb, const u16* __restrict__ k_pe, u16* __restrict__ k_full){
  const int tok = blockIdx.x;
  const int b = tok>>11, sidx = tok&2047;
  const int t = threadIdx.x;
  const int kh = t>>5, seg = t&31;
  short8 v;
  if(seg < 16) v = *(const short8*)(kvb + (size_t)tok*2048 + kh*256 + seg*8);
  else         v = *(const short8*)(k_pe + (size_t)tok*128 + (seg-16)*8);
  *(short8*)(k_full + (((size_t)(b*8 + kh))*2048 + sidx)*256 + seg*8) = v;
}

// ---------- v_t tile-major: [b][kvh][kt(64)][hd(128)][kv(32)] ----------
__global__ void k_v_t(const u16* __restrict__ kvb, u16* __restrict__ v_t){
  __shared__ u16 tile[32][33];
  const int sb = blockIdx.x*32, hb = blockIdx.y*32;
  const int bk = blockIdx.z;
  const int b = bk>>3, kh = bk&7;
  const int tx = threadIdx.x, ty = threadIdx.y;
#pragma unroll
  for(int i=0;i<4;i++){
    int sidx = sb + ty + i*8;
    tile[ty+i*8][tx] = kvb[((size_t)(b*2048 + sidx))*2048 + kh*256 + 128 + hb + tx];
  }
  __syncthreads();
#pragma unroll
  for(int i=0;i<4;i++){
    int hd = hb + ty + i*8;
    // tile index = blockIdx.x (32 s per tile), within-tile kv = tx
    v_t[(((size_t)bk*64 + blockIdx.x)*128 + hd)*32 + tx] = tile[tx][ty+i*8];
  }
}

// ---------- flash attention, S^T layout, XCD-swizzled 1D grid ----------
// 512 blocks. KVBLK=32. K: 2x16KB LDS via gl_lds (XOR-src-swizzle).
// V: 2x[128][40] padded LDS, reg-staged coalesced from tile-major v_t
// (T14: loads at top of iter, ds_write after PV). P: per-wave [16][40].
__global__ __launch_bounds__(256)
void k_attn(const u16* __restrict__ q_fin, const u16* __restrict__ k_full,
            const u16* __restrict__ v_t, u16* __restrict__ attn){
  __shared__ __align__(16) u16 lsK[2*8192];     // 32768 B : 2 x [32][256] swizzled
  __shared__ __align__(16) u16 lsV[2*128*40];   // 20480 B : 2 x [128][40] padded
  __shared__ __align__(16) u16 lsP[4*16*40];    //  5120 B : per-wave [16][40]
  // decode swizzled id: blk = hi*256 + i*8 + (g&7), hi = g>>3
  const int blk = blockIdx.x;
  const int g  = (blk>>8)*8 + (blk&7);   // 0..15 = b*8+kvh
  const int i  = (blk>>3)&31;            // 0..31 within group
  const int b  = g>>3, kvh = g&7;
  const int pr = i&15;
  const int h  = kvh*2 + (i>>4);
  const int t = threadIdx.x, wv = t>>6, ln = t&63;
  const int fq = ln&15, gq = ln>>4;
  const u16* kbase = k_full + ((size_t)(b*8 + kvh))*2048*256;
  const u16* vbase = v_t + ((size_t)(b*8 + kvh))*128*2048;
  u16* Pw = &lsP[wv*16*40];

  // K staging: per-lane swizzled global byte offsets within a 16 KiB tile.
  // lane covers LDS bytes o = s4*4096 + wv*1024 + ln*16 (linear dest);
  // source = (row = o>>9) * 512 + ((o&511) ^ ((row&7)<<4)).
  int soff[4];
#pragma unroll
  for(int s4=0;s4<4;s4++){
    int o = s4*4096 + wv*1024 + ln*16;
    int row = o>>9, colb = o&511;
    soff[s4] = row*512 + (colb ^ ((row&7)<<4));
  }
  // QK-read swizzled column byte offsets (loop-invariant per lane)
  const int swz = (fq&7)<<4;
  int cb[8];
#pragma unroll
  for(int c=0;c<8;c++) cb[c] = (gq*16 + c*64) ^ swz;
  const int rowb = fq*512;
  // V staging: thread covers 32B of the contiguous 8KB tile
  const int vrow = t>>1, vcol = (t&1)*16;   // [128][32] coords

  for(int half=0; half<2; half++){
    const int qt = half ? (31-pr) : pr;
    const int last = 2*qt + 1;
    short8 qf[8];
    const u16* qb = q_fin + (((size_t)(b*16 + h))*2048 + qt*64 + wv*16 + fq)*256;
#pragma unroll
    for(int c=0;c<8;c++) qf[c] = *(const short8*)(qb + c*32 + gq*8);
    floatx4 oacc[8];
#pragma unroll
    for(int ii=0;ii<8;ii++) oacc[ii] = (floatx4){0.f,0.f,0.f,0.f};
    float mprev = -3e38f, lsum = 0.f;

    // prologue: K tile0 -> buf0 (gl_lds), V tile0 -> buf0 (reg-staged)
#pragma unroll
    for(int s4=0;s4<4;s4++)
      gl_lds16((const u16*)((const char*)kbase + soff[s4]), &lsK[s4*2048 + wv*512]);
    {
      const u16* vg = vbase + (size_t)t*16;
      short8 v0 = *(const short8*)vg;
      short8 v1 = *(const short8*)(vg+8);
      *(short8*)&lsV[vrow*40 + vcol]     = v0;
      *(short8*)&lsV[vrow*40 + vcol + 8] = v1;
    }
    __syncthreads();

    int cur = 0;
    for(int kt=0; kt<=last; kt++){
      short8 vr0, vr1;
      // issue next tile's K stage + V loads (fly under compute)
      if(kt < last){
        const char* ktile = (const char*)kbase + (size_t)(kt+1)*16384;
        u16* kdst = &lsK[(cur^1)*8192];
#pragma unroll
        for(int s4=0;s4<4;s4++)
          gl_lds16((const u16*)(ktile + soff[s4]), kdst + s4*2048 + wv*512);
        const u16* vg = vbase + (size_t)(kt+1)*4096 + t*16;
        vr0 = *(const short8*)vg;
        vr1 = *(const short8*)(vg+8);
      }
      const char* Kc = (const char*)lsK + cur*16384;
      const u16* Vc = &lsV[cur*5120];

      // S^T = K · Q^T : rows kv (32), cols q (16)
      floatx4 sc[2];
#pragma unroll
      for(int ns=0;ns<2;ns++) sc[ns] = (floatx4){0.f,0.f,0.f,0.f};
#pragma unroll
      for(int ns=0;ns<2;ns++){
#pragma unroll
        for(int c=0;c<8;c++){
          short8 kf = *(const short8*)(Kc + ns*8192 + rowb + cb[c]);
          sc[ns] = mfma16(kf, qf[c], sc[ns]);
        }
      }
      if(kt >= 2*qt){  // diagonal tiles: mask kv > q
        const int off = (kt - 2*qt)*32;
        const int qloc = wv*16 + fq;
#pragma unroll
        for(int ns=0;ns<2;ns++)
#pragma unroll
          for(int r=0;r<4;r++)
            if(off + ns*16 + gq*4 + r > qloc) sc[ns][r] = -1e30f;
      }
      // per-q (column) max
      float mloc = -3e38f;
#pragma unroll
      for(int ns=0;ns<2;ns++)
#pragma unroll
        for(int r=0;r<4;r++) mloc = fmaxf(mloc, sc[ns][r]);
      mloc = fmaxf(mloc, __shfl_xor(mloc, 16));
      mloc = fmaxf(mloc, __shfl_xor(mloc, 32));
      const float mn = fmaxf(mprev, mloc);
      const float alpha = exp2f(mprev - mn);
      float ps = 0.f;
#pragma unroll
      for(int ns=0;ns<2;ns++)
#pragma unroll
        for(int r=0;r<4;r++){
          float p = exp2f(sc[ns][r] - mn);
          sc[ns][r] = p;
          ps += p;
        }
      ps += __shfl_xor(ps, 16);
      ps += __shfl_xor(ps, 32);
      lsum = lsum*alpha + ps;
      mprev = mn;

      // P -> per-wave LDS in A-layout: row q=fq, cols kv (32)
#pragma unroll
      for(int ns=0;ns<2;ns++){
        u32 p01 = (u32)f2bf(sc[ns][0]) | ((u32)f2bf(sc[ns][1])<<16);
        u32 p23 = (u32)f2bf(sc[ns][2]) | ((u32)f2bf(sc[ns][3])<<16);
        uint2 pk; pk.x = p01; pk.y = p23;
        *(uint2*)&Pw[fq*40 + ns*16 + gq*4] = pk;
      }
      // rescale O rows (row q = gq*4+r)
      float alphaO[4];
#pragma unroll
      for(int r=0;r<4;r++) alphaO[r] = __shfl(alpha, gq*4 + r);
#pragma unroll
      for(int hs=0;hs<8;hs++)
#pragma unroll
        for(int r=0;r<4;r++) oacc[hs][r] *= alphaO[r];
      __builtin_amdgcn_s_waitcnt(0xC07F);  // lgkmcnt(0): P visible to own wave

      // O += P · V  (V from LDS; K=32 in one MFMA per hd-block)
      short8 pa = *(const short8*)&Pw[fq*40 + gq*8];
#pragma unroll
      for(int hs=0;hs<8;hs++){
        short8 vb = *(const short8*)&Vc[(hs*16 + fq)*40 + gq*8];
        oacc[hs] = mfma16(pa, vb, oacc[hs]);
      }
      // write next V tile into the free buffer (waits its loads only)
      if(kt < last){
        u16* vd = &lsV[(cur^1)*5120 + vrow*40 + vcol];
        *(short8*)vd     = vr0;
        *(short8*)(vd+8) = vr1;
      }
      __syncthreads();   // K gl_lds(kt+1) drained here (overlapped all iter)
      cur ^= 1;
    }
    const float inv = 1.f / lsum;
    float invO[4];
#pragma unroll
    for(int r=0;r<4;r++) invO[r] = __shfl(inv, gq*4 + r);
#pragma unroll
    for(int hs=0;hs<8;hs++)
#pragma unroll
      for(int r=0;r<4;r++){
        const int qi = qt*64 + wv*16 + gq*4 + r;
        attn[(((size_t)(b*2048 + qi))*16 + h)*128 + hs*16 + fq] = f2bf(oacc[hs][r]*invO[r]);
      }
  }
}

extern "C" void kernel_launch(void* const* d_in, const int* in_sizes, int n_in,
                              void* d_out, int out_size, void* d_ws, size_t ws_size,
                              hipStream_t stream){
  const float* x    = (const float*)d_in[0];
  const float* wq   = (const float*)d_in[1];
  const float* wkva = (const float*)d_in[2];
  const float* kvsc = (const float*)d_in[3];
  const float* wkvb = (const float*)d_in[4];
  const float* wo   = (const float*)d_in[5];
  const int* pid  = (const int*)d_in[7];
  float* out = (float*)d_out;

  char* w = (char*)d_ws;
  size_t off = 0;
  auto alloc = [&](size_t bytes)->void*{
    void* p = (void*)(w + off);
    off += (bytes + 255) & ~(size_t)255;
    return p;
  };
  u16*   x_bf   = (u16*)alloc((size_t)4096*2048*2);
  u16*   wq_t   = (u16*)alloc((size_t)4096*2048*2);
  u16*   wkva_t = (u16*)alloc((size_t)640*2048*2);
  u16*   wkvb_t = (u16*)alloc((size_t)2048*512*2);
  u16*   wo_t   = (u16*)alloc((size_t)2048*2048*2);
  float* cosT   = (float*)alloc((size_t)2048*64*4);
  float* sinT   = (float*)alloc((size_t)2048*64*4);
  u16*   q_raw  = (u16*)alloc((size_t)4096*4096*2);
  float* kvf    = (float*)alloc((size_t)4096*640*4);
  u16*   kv_cn  = (u16*)alloc((size_t)4096*512*2);
  u16*   k_pe   = (u16*)alloc((size_t)4096*128*2);
  u16*   kvb    = (u16*)alloc((size_t)4096*2048*2);
  u16*   q_fin  = (u16*)alloc((size_t)4096*4096*2);
  u16*   k_full = (u16*)alloc((size_t)2*8*2048*256*2);
  u16*   v_t    = (u16*)alloc((size_t)2*8*128*2048*2);
  u16*   attn   = (u16*)alloc((size_t)4096*2048*2);

  k_f2b<<<8192, 256, 0, stream>>>(x, x_bf, (size_t)4096*2048);
  k_transpose<<<dim3(128, 64), dim3(32,8), 0, stream>>>(wq,   wq_t,   2048, 4096);
  k_transpose<<<dim3(20,  64), dim3(32,8), 0, stream>>>(wkva, wkva_t, 2048, 640);
  k_transpose<<<dim3(64,  16), dim3(32,8), 0, stream>>>(wkvb, wkvb_t, 512,  2048);
  k_transpose<<<dim3(64,  64), dim3(32,8), 0, stream>>>(wo,   wo_t,   2048, 2048);
  k_rope_table<<<512, 256, 0, stream>>>(cosT, sinT);

  k_gemm_bt<0><<<dim3(32, 32), 256, 0, stream>>>(x_bf, wq_t, q_raw, 4096, 4096, 2048);
  k_gemm_bt<1><<<dim3(5,  32), 256, 0, stream>>>(x_bf, wkva_t, kvf, 4096, 640, 2048);
  k_ln_rope<<<4096, 256, 0, stream>>>(kvf, kvsc, pid, cosT, sinT, kv_cn, k_pe);
  k_gemm_bt<0><<<dim3(16, 32), 256, 0, stream>>>(kv_cn, wkvb_t, kvb, 4096, 2048, 512);
  k_q_rope<<<4096, 256, 0, stream>>>(q_raw, pid, cosT, sinT, q_fin);
  k_build_k<<<4096, 256, 0, stream>>>(kvb, k_pe, k_full);
  k_v_t<<<dim3(64, 4, 16), dim3(32,8), 0, stream>>>(kvb, v_t);
  k_attn<<<512, 256, 0, stream>>>(q_fin, k_full, v_t, attn);
  k_gemm_bt<1><<<dim3(16, 32), 256, 0, stream>>>(attn, wo_t, out, 4096, 2048, 2048);
}

// Round 4
// 517.886 us; speedup vs baseline: 1.8142x; 1.0151x over previous
//
#include <hip/hip_runtime.h>

// MLA forward. Inputs f32, internal bf16 MFMA 16x16x32, output f32.
// R11: V never touches LDS — tile-major v_t makes each wave's PV B-frags a
// permuted-contiguous 1KB load (8x coalesced b128 -> MFMA frags directly).
// LDS 58.4KB -> 37.9KB; grid 512 -> 1024 single-q-tile blocks (big-first,
// XCD-swizzled) + launch_bounds(256,3) => 3 blocks/CU (was 2).
// Softmax VALU cuts: T13 defer-max (skip rescale unless __any(m grows >8)),
// v_cvt_pk_bf16_f32 P-pack (4 instrs vs ~36 bit-twiddle ops).

typedef __attribute__((ext_vector_type(8))) short short8;
typedef __attribute__((ext_vector_type(4))) float floatx4;
typedef unsigned short u16;
typedef unsigned int u32;

__device__ __forceinline__ float bf2f(u16 u){ u32 x=((u32)u)<<16; return __builtin_bit_cast(float,x); }
__device__ __forceinline__ u16 f2bf(float f){ u32 x=__builtin_bit_cast(u32,f); return (u16)((x + 0x7fffu + ((x>>16)&1u))>>16); }

__device__ __forceinline__ floatx4 mfma16(short8 a, short8 b, floatx4 c){
  return __builtin_amdgcn_mfma_f32_16x16x32_bf16(a,b,c,0,0,0);
}

// async global->LDS, 16B per lane. LDS dest = wave-uniform base + lane*16.
__device__ __forceinline__ void gl_lds16(const u16* g, u16* l){
  __builtin_amdgcn_global_load_lds((const __attribute__((address_space(1))) void*)g,
                                   (__attribute__((address_space(3))) void*)l, 16, 0, 0);
}

// ---------- f32 -> bf16 elementwise (for x) ----------
__global__ __launch_bounds__(256)
void k_f2b(const float* __restrict__ in, u16* __restrict__ out, size_t n){
  size_t i = ((size_t)blockIdx.x*256 + threadIdx.x)*4;
  if(i >= n) return;
  float4 v = *(const float4*)(in + i);
  out[i+0] = f2bf(v.x); out[i+1] = f2bf(v.y); out[i+2] = f2bf(v.z); out[i+3] = f2bf(v.w);
}

// ---------- transpose + convert: f32 [K,N] -> bf16 [N,K] ----------
__global__ void k_transpose(const float* __restrict__ in, u16* __restrict__ out, int K, int N){
  __shared__ u16 tile[32][33];
  const int kb = blockIdx.y*32, nb = blockIdx.x*32;
  const int tx = threadIdx.x, ty = threadIdx.y;
#pragma unroll
  for(int i=0;i<4;i++) tile[ty+i*8][tx] = f2bf(in[(size_t)(kb+ty+i*8)*N + nb + tx]);
  __syncthreads();
#pragma unroll
  for(int i=0;i<4;i++) out[(size_t)(nb+ty+i*8)*K + kb + tx] = tile[tx][ty+i*8];
}

// ---------- rope table (fp64 for large-angle accuracy) ----------
__global__ void k_rope_table(float* __restrict__ cosT, float* __restrict__ sinT){
  int idx = blockIdx.x*256 + threadIdx.x;
  if(idx >= 2048*64) return;
  int p = idx>>6, i = idx&63;
  double freq = pow(10000.0, -(double)(2*i)/128.0) * 40.0;
  float ff = (float)freq;
  float ang = (float)((double)p * (double)ff);
  cosT[idx] = (float)cos((double)ang);
  sinT[idx] = (float)sin((double)ang);
}

// ---------- GEMM: A[M,K] bf16 @ Bt[N,K] bf16 -> C[M,N] (bf16 or f32) ----------
template<int OUTF32>
__global__ __launch_bounds__(256)
void k_gemm_bt(const u16* __restrict__ A, const u16* __restrict__ Bt, void* __restrict__ Cout,
               int M, int N, int K){
  __shared__ __align__(16) u16 lsA[128*32];
  __shared__ __align__(16) u16 lsB[128*32];
  const int t = threadIdx.x;
  const int m0 = blockIdx.y*128, n0 = blockIdx.x*128;
  const int wv = t>>6, ln = t&63;
  const int wr = (wv>>1)*64, wc = (wv&1)*64;
  const int fr = ln&15, kh = (ln>>4)*8;
  const int srow = wv*16 + (ln>>2), sk = (ln&3)*8;
  const u16* Ag = A + (size_t)(m0 + srow)*K + sk;
  const u16* Bg = Bt + (size_t)(n0 + srow)*K + sk;
  u16* lA0 = &lsA[wv*512];
  u16* lB0 = &lsB[wv*512];
  floatx4 acc[4][4];
#pragma unroll
  for(int i=0;i<4;i++)
#pragma unroll
    for(int j=0;j<4;j++) acc[i][j] = (floatx4){0.f,0.f,0.f,0.f};
  for(int k0=0;k0<K;k0+=32){
    __syncthreads();
    gl_lds16(Ag + k0,              lA0);
    gl_lds16(Ag + (size_t)64*K + k0, lA0 + 2048);
    gl_lds16(Bg + k0,              lB0);
    gl_lds16(Bg + (size_t)64*K + k0, lB0 + 2048);
    __syncthreads();
    short8 af[4], bf[4];
#pragma unroll
    for(int i=0;i<4;i++) af[i] = *(const short8*)&lsA[(wr + i*16 + fr)*32 + kh];
#pragma unroll
    for(int i=0;i<4;i++) bf[i] = *(const short8*)&lsB[(wc + i*16 + fr)*32 + kh];
#pragma unroll
    for(int mi=0;mi<4;mi++)
#pragma unroll
      for(int ni=0;ni<4;ni++) acc[mi][ni] = mfma16(af[mi], bf[ni], acc[mi][ni]);
  }
  const int r0 = (ln>>4)*4, c0 = ln&15;
#pragma unroll
  for(int mi=0;mi<4;mi++)
#pragma unroll
    for(int ni=0;ni<4;ni++){
      const int row = m0 + wr + mi*16 + r0;
      const int col = n0 + wc + ni*16 + c0;
#pragma unroll
      for(int r=0;r<4;r++){
        float v = acc[mi][ni][r];
        if(OUTF32) ((float*)Cout)[(size_t)(row+r)*N + col] = v;
        else       ((u16*)Cout)[(size_t)(row+r)*N + col] = f2bf(v);
      }
    }
}

// ---------- layernorm(kv[:512]) -> bf16 ; rope(kv[512:640]) -> k_pe bf16 ----------
__global__ __launch_bounds__(256)
void k_ln_rope(const float* __restrict__ kv, const float* __restrict__ scale,
               const int* __restrict__ pid, const float* __restrict__ cosT,
               const float* __restrict__ sinT, u16* __restrict__ kv_cn, u16* __restrict__ k_pe){
  const int tok = blockIdx.x;
  const int t = threadIdx.x;
  const float* row = kv + (size_t)tok*640;
  float v0 = row[2*t], v1 = row[2*t+1];
  float s = v0+v1, ss = v0*v0+v1*v1;
#pragma unroll
  for(int off=32; off>=1; off>>=1){ s += __shfl_xor(s,off); ss += __shfl_xor(ss,off); }
  __shared__ float red[8];
  if((t&63)==0){ red[t>>6]=s; red[4+(t>>6)]=ss; }
  __syncthreads();
  float S4 = red[0]+red[1]+red[2]+red[3];
  float SS4 = red[4]+red[5]+red[6]+red[7];
  float mean = S4*(1.f/512.f);
  float var = SS4*(1.f/512.f) - mean*mean;
  float inv = rsqrtf(var + 1e-5f);
  kv_cn[(size_t)tok*512 + 2*t]   = f2bf((v0-mean)*inv*scale[2*t]);
  kv_cn[(size_t)tok*512 + 2*t+1] = f2bf((v1-mean)*inv*scale[2*t+1]);
  if(t < 128){
    const int sidx = tok & 2047;
    const int p = pid[sidx];
    const int i = t>>1;
    float c = cosT[p*64+i], sn = sinT[p*64+i];
    float xr = row[512+2*i], xi = row[512+2*i+1];
    float val = (t&1) ? (xr*sn + xi*c) : (xr*c - xi*sn);
    k_pe[(size_t)tok*128 + t] = f2bf(val);
  }
}

// ---------- q: copy nope, rope pe; fold scale*log2e; layout [B,H,S,256] ----------
// vectorized: thread t handles head h=t>>4, 16 elems at seg*16 (short8 x2)
__global__ __launch_bounds__(256)
void k_q_rope(const u16* __restrict__ q_raw, const int* __restrict__ pid,
              const float* __restrict__ cosT, const float* __restrict__ sinT,
              u16* __restrict__ q_fin){
  const float QS = (float)(0.08838834764831845 * 1.4426950408889634); // /sqrt(128) * log2(e)
  const int tok = blockIdx.x;
  const int b = tok>>11, sidx = tok&2047;
  const int t = threadIdx.x;
  const int p = pid[sidx];
  const int h = t>>4, seg = t&15;
  const u16* src = q_raw + (size_t)tok*4096 + h*256 + seg*16;
  u16* dst = q_fin + (((size_t)(b*16 + h))*2048 + sidx)*256 + seg*16;
  short8 a = *(const short8*)src;
  short8 bv = *(const short8*)(src+8);
  short8 oa, ob;
  if(seg < 8){
#pragma unroll
    for(int j=0;j<8;j++){
      oa[j] = (short)f2bf(bf2f((u16)a[j])*QS);
      ob[j] = (short)f2bf(bf2f((u16)bv[j])*QS);
    }
  } else {
    const int i0 = seg*8 - 64;   // pair index base within 64 rope pairs
#pragma unroll
    for(int j=0;j<4;j++){
      float c = cosT[p*64 + i0 + j], sn = sinT[p*64 + i0 + j];
      float xr = bf2f((u16)a[2*j]), xi = bf2f((u16)a[2*j+1]);
      oa[2*j]   = (short)f2bf((xr*c - xi*sn)*QS);
      oa[2*j+1] = (short)f2bf((xr*sn + xi*c)*QS);
    }
#pragma unroll
    for(int j=0;j<4;j++){
      float c = cosT[p*64 + i0 + 4 + j], sn = sinT[p*64 + i0 + 4 + j];
      float xr = bf2f((u16)bv[2*j]), xi = bf2f((u16)bv[2*j+1]);
      ob[2*j]   = (short)f2bf((xr*c - xi*sn)*QS);
      ob[2*j+1] = (short)f2bf((xr*sn + xi*c)*QS);
    }
  }
  *(short8*)dst = oa;
  *(short8*)(dst+8) = ob;
}

// ---------- k_full[b][kvh][s][256] = concat(k_nope, k_pe), vectorized ----------
__global__ __launch_bounds__(256)
void k_build_k(const u16* __restrict__ kvb, const u16* __restrict__ k_pe, u16* __restrict__ k_full){
  const int tok = blockIdx.x;
  const int b = tok>>11, sidx = tok&2047;
  const int t = threadIdx.x;
  const int kh = t>>5, seg = t&31;
  short8 v;
  if(seg < 16) v = *(const short8*)(kvb + (size_t)tok*2048 + kh*256 + seg*8);
  else         v = *(const short8*)(k_pe + (size_t)tok*128 + (seg-16)*8);
  *(short8*)(k_full + (((size_t)(b*8 + kh))*2048 + sidx)*256 + seg*8) = v;
}

// ---------- v_t tile-major: [b][kvh][kt(64)][hd(128)][kv(32)] ----------
__global__ void k_v_t(const u16* __restrict__ kvb, u16* __restrict__ v_t){
  __shared__ u16 tile[32][33];
  const int sb = blockIdx.x*32, hb = blockIdx.y*32;
  const int bk = blockIdx.z;
  const int b = bk>>3, kh = bk&7;
  const int tx = threadIdx.x, ty = threadIdx.y;
#pragma unroll
  for(int i=0;i<4;i++){
    int sidx = sb + ty + i*8;
    tile[ty+i*8][tx] = kvb[((size_t)(b*2048 + sidx))*2048 + kh*256 + 128 + hb + tx];
  }
  __syncthreads();
#pragma unroll
  for(int i=0;i<4;i++){
    int hd = hb + ty + i*8;
    // tile index = blockIdx.x (32 s per tile), within-tile kv = tx
    v_t[(((size_t)bk*64 + blockIdx.x)*128 + hd)*32 + tx] = tile[tx][ty+i*8];
  }
}

// ---------- flash attention, S^T layout, XCD-swizzled 1D grid ----------
// 1024 blocks, one 64-q tile each (big tiles dispatched first). blk%8 = kvh
// -> all blocks sharing one kvh's K/V land on one XCD (2 b-groups x 1.5MB
// = 3MB L2 working set). KVBLK=32.
// K: 2x16KB LDS via gl_lds (XOR-src-swizzle), dbuf, 1 barrier/iter.
// V: NO LDS — tile-major v_t makes each wave's 8 PV B-frags a permuted-
//    contiguous 1KB global load each (L1-resident across the 4 waves).
// Softmax: T13 defer-max (skip rescale unless max grows >8) + cvt_pk P-pack.
__global__ __launch_bounds__(256, 3)
void k_attn(const u16* __restrict__ q_fin, const u16* __restrict__ k_full,
            const u16* __restrict__ v_t, u16* __restrict__ attn){
  __shared__ __align__(16) u16 lsK[2*8192];   // 32768 B : 2 x [32][256] swizzled
  __shared__ __align__(16) u16 lsP[4*16*40];  //  5120 B : per-wave [16][40]
  // decode: blk = qr*16 + bb*8 + kvh ; qr 0..63 -> (qt desc, h parity)
  const int blk = blockIdx.x;
  const int kvh = blk&7;
  const int bb  = (blk>>3)&1;
  const int qr  = blk>>4;
  const int qt  = 31 - (qr>>1);          // big tiles first
  const int h   = kvh*2 + (qr&1);
  const int t = threadIdx.x, wv = t>>6, ln = t&63;
  const int fq = ln&15, gq = ln>>4;
  const u16* kbase = k_full + ((size_t)(bb*8 + kvh))*2048*256;
  const u16* vbase = v_t + ((size_t)(bb*8 + kvh))*128*2048;
  u16* Pw = &lsP[wv*16*40];

  // K staging: per-lane swizzled global byte offsets within a 16 KiB tile.
  // lane covers LDS bytes o = s4*4096 + wv*1024 + ln*16 (linear dest);
  // source = (row = o>>9) * 512 + ((o&511) ^ ((row&7)<<4)).
  int soff[4];
#pragma unroll
  for(int s4=0;s4<4;s4++){
    int o = s4*4096 + wv*1024 + ln*16;
    int row = o>>9, colb = o&511;
    soff[s4] = row*512 + (colb ^ ((row&7)<<4));
  }
  // QK-read swizzled column byte offsets (loop-invariant per lane)
  const int swz = (fq&7)<<4;
  int cb[8];
#pragma unroll
  for(int c=0;c<8;c++) cb[c] = (gq*16 + c*64) ^ swz;
  const int rowb = fq*512;
  // V frag base: lane (fq,gq) reads V[hd=hs*16+fq][kv=gq*8..+7] of tile kt
  const u16* vfp = vbase + (size_t)fq*32 + gq*8;

  const int last = 2*qt + 1;
  short8 qf[8];
  const u16* qb = q_fin + (((size_t)(bb*16 + h))*2048 + qt*64 + wv*16 + fq)*256;
#pragma unroll
  for(int c=0;c<8;c++) qf[c] = *(const short8*)(qb + c*32 + gq*8);
  floatx4 oacc[8];
#pragma unroll
  for(int ii=0;ii<8;ii++) oacc[ii] = (floatx4){0.f,0.f,0.f,0.f};
  float mprev = -3e38f, lsum = 0.f;

  // prologue: K tile0 -> buf0
#pragma unroll
  for(int s4=0;s4<4;s4++)
    gl_lds16((const u16*)((const char*)kbase + soff[s4]), &lsK[s4*2048 + wv*512]);
  __syncthreads();

  int cur = 0;
  for(int kt=0; kt<=last; kt++){
    // issue next K tile stage (flies under the whole iteration)
    if(kt < last){
      const char* ktile = (const char*)kbase + (size_t)(kt+1)*16384;
      u16* kdst = &lsK[(cur^1)*8192];
#pragma unroll
      for(int s4=0;s4<4;s4++)
        gl_lds16((const u16*)(ktile + soff[s4]), kdst + s4*2048 + wv*512);
    }
    // V frags for this tile: 8 permuted-contiguous 1KB loads (L1/L2-hit)
    short8 vf[8];
#pragma unroll
    for(int hs=0;hs<8;hs++)
      vf[hs] = *(const short8*)(vfp + (size_t)kt*4096 + hs*512);

    const char* Kc = (const char*)lsK + cur*16384;
    // S^T = K · Q^T : rows kv (32), cols q (16)
    floatx4 sc[2];
#pragma unroll
    for(int ns=0;ns<2;ns++) sc[ns] = (floatx4){0.f,0.f,0.f,0.f};
#pragma unroll
    for(int ns=0;ns<2;ns++){
#pragma unroll
      for(int c=0;c<8;c++){
        short8 kf = *(const short8*)(Kc + ns*8192 + rowb + cb[c]);
        sc[ns] = mfma16(kf, qf[c], sc[ns]);
      }
    }
    if(kt >= 2*qt){  // diagonal tiles: mask kv > q
      const int off = (kt - 2*qt)*32;
      const int qloc = wv*16 + fq;
#pragma unroll
      for(int ns=0;ns<2;ns++)
#pragma unroll
        for(int r=0;r<4;r++)
          if(off + ns*16 + gq*4 + r > qloc) sc[ns][r] = -1e30f;
    }
    // per-q (column) max
    float mloc = -3e38f;
#pragma unroll
    for(int ns=0;ns<2;ns++)
#pragma unroll
      for(int r=0;r<4;r++) mloc = fmaxf(mloc, sc[ns][r]);
    mloc = fmaxf(mloc, __shfl_xor(mloc, 16));
    mloc = fmaxf(mloc, __shfl_xor(mloc, 32));
    // T13 defer-max: only rescale when the running max grows by >8 (log2)
    if(__any(mloc > mprev + 8.f)){
      const float mn = fmaxf(mprev, mloc);
      const float alpha = exp2f(mprev - mn);
      lsum *= alpha;
      float alphaO[4];
#pragma unroll
      for(int r=0;r<4;r++) alphaO[r] = __shfl(alpha, gq*4 + r);
#pragma unroll
      for(int hs=0;hs<8;hs++)
#pragma unroll
        for(int r=0;r<4;r++) oacc[hs][r] *= alphaO[r];
      mprev = mn;
    }
    float ps = 0.f;
#pragma unroll
    for(int ns=0;ns<2;ns++)
#pragma unroll
      for(int r=0;r<4;r++){
        float p = exp2f(sc[ns][r] - mprev);
        sc[ns][r] = p;
        ps += p;
      }
    ps += __shfl_xor(ps, 16);
    ps += __shfl_xor(ps, 32);
    lsum += ps;

    // P -> per-wave LDS in A-layout (row q=fq, cols kv), packed via cvt_pk
#pragma unroll
    for(int ns=0;ns<2;ns++){
      u32 p01, p23;
      asm("v_cvt_pk_bf16_f32 %0, %1, %2" : "=v"(p01) : "v"(sc[ns][0]), "v"(sc[ns][1]));
      asm("v_cvt_pk_bf16_f32 %0, %1, %2" : "=v"(p23) : "v"(sc[ns][2]), "v"(sc[ns][3]));
      uint2 pk; pk.x = p01; pk.y = p23;
      *(uint2*)&Pw[fq*40 + ns*16 + gq*4] = pk;
    }
    __builtin_amdgcn_s_waitcnt(0xC07F);  // lgkmcnt(0): P visible to own wave

    // O += P · V  (V from registers)
    short8 pa = *(const short8*)&Pw[fq*40 + gq*8];
#pragma unroll
    for(int hs=0;hs<8;hs++)
      oacc[hs] = mfma16(pa, vf[hs], oacc[hs]);

    __syncthreads();   // K gl_lds(kt+1) drained here (overlapped all iter)
    cur ^= 1;
  }
  const float inv = 1.f / lsum;
  float invO[4];
#pragma unroll
  for(int r=0;r<4;r++) invO[r] = __shfl(inv, gq*4 + r);
#pragma unroll
  for(int hs=0;hs<8;hs++)
#pragma unroll
    for(int r=0;r<4;r++){
      const int qi = qt*64 + wv*16 + gq*4 + r;
      attn[(((size_t)(bb*2048 + qi))*16 + h)*128 + hs*16 + fq] = f2bf(oacc[hs][r]*invO[r]);
    }
}

extern "C" void kernel_launch(void* const* d_in, const int* in_sizes, int n_in,
                              void* d_out, int out_size, void* d_ws, size_t ws_size,
                              hipStream_t stream){
  const float* x    = (const float*)d_in[0];
  const float* wq   = (const float*)d_in[1];
  const float* wkva = (const float*)d_in[2];
  const float* kvsc = (const float*)d_in[3];
  const float* wkvb = (const float*)d_in[4];
  const float* wo   = (const float*)d_in[5];
  const int* pid  = (const int*)d_in[7];
  float* out = (float*)d_out;

  char* w = (char*)d_ws;
  size_t off = 0;
  auto alloc = [&](size_t bytes)->void*{
    void* p = (void*)(w + off);
    off += (bytes + 255) & ~(size_t)255;
    return p;
  };
  u16*   x_bf   = (u16*)alloc((size_t)4096*2048*2);
  u16*   wq_t   = (u16*)alloc((size_t)4096*2048*2);
  u16*   wkva_t = (u16*)alloc((size_t)640*2048*2);
  u16*   wkvb_t = (u16*)alloc((size_t)2048*512*2);
  u16*   wo_t   = (u16*)alloc((size_t)2048*2048*2);
  float* cosT   = (float*)alloc((size_t)2048*64*4);
  float* sinT   = (float*)alloc((size_t)2048*64*4);
  u16*   q_raw  = (u16*)alloc((size_t)4096*4096*2);
  float* kvf    = (float*)alloc((size_t)4096*640*4);
  u16*   kv_cn  = (u16*)alloc((size_t)4096*512*2);
  u16*   k_pe   = (u16*)alloc((size_t)4096*128*2);
  u16*   kvb    = (u16*)alloc((size_t)4096*2048*2);
  u16*   q_fin  = (u16*)alloc((size_t)4096*4096*2);
  u16*   k_full = (u16*)alloc((size_t)2*8*2048*256*2);
  u16*   v_t    = (u16*)alloc((size_t)2*8*128*2048*2);
  u16*   attn   = (u16*)alloc((size_t)4096*2048*2);

  k_f2b<<<8192, 256, 0, stream>>>(x, x_bf, (size_t)4096*2048);
  k_transpose<<<dim3(128, 64), dim3(32,8), 0, stream>>>(wq,   wq_t,   2048, 4096);
  k_transpose<<<dim3(20,  64), dim3(32,8), 0, stream>>>(wkva, wkva_t, 2048, 640);
  k_transpose<<<dim3(64,  16), dim3(32,8), 0, stream>>>(wkvb, wkvb_t, 512,  2048);
  k_transpose<<<dim3(64,  64), dim3(32,8), 0, stream>>>(wo,   wo_t,   2048, 2048);
  k_rope_table<<<512, 256, 0, stream>>>(cosT, sinT);

  k_gemm_bt<0><<<dim3(32, 32), 256, 0, stream>>>(x_bf, wq_t, q_raw, 4096, 4096, 2048);
  k_gemm_bt<1><<<dim3(5,  32), 256, 0, stream>>>(x_bf, wkva_t, kvf, 4096, 640, 2048);
  k_ln_rope<<<4096, 256, 0, stream>>>(kvf, kvsc, pid, cosT, sinT, kv_cn, k_pe);
  k_gemm_bt<0><<<dim3(16, 32), 256, 0, stream>>>(kv_cn, wkvb_t, kvb, 4096, 2048, 512);
  k_q_rope<<<4096, 256, 0, stream>>>(q_raw, pid, cosT, sinT, q_fin);
  k_build_k<<<4096, 256, 0, stream>>>(kvb, k_pe, k_full);
  k_v_t<<<dim3(64, 4, 16), dim3(32,8), 0, stream>>>(kvb, v_t);
  k_attn<<<1024, 256, 0, stream>>>(q_fin, k_full, v_t, attn);
  k_gemm_bt<1><<<dim3(16, 32), 256, 0, stream>>>(attn, wo_t, out, 4096, 2048, 2048);
}